// Round 13
// baseline (169.833 us; speedup 1.0000x reference)
//
#include <hip/hip_runtime.h>
#include <math.h>

#define Hdim   2048
#define HF4    512
#define MARGIN 2e-5f
#define CAPF   16384
#define PROBE0 1237
#define PROBE1 20011

// ws layout (byte offsets)
#define WS_FCNT  0
#define WS_BAD   4
#define WS_PROBE 64            // 128 floats (2 probe tokens x 64 logits)
#define WS_FLIST 1024          // CAPF ints = 64 KB
#define WS_WH    (128*1024)    // 131072 bf16 = 256 KB
#define WS_WL    (384*1024)    // 131072 bf16 = 256 KB
#define WS_NEED  (640*1024)

typedef float f32x4 __attribute__((ext_vector_type(4)));
typedef short bf8   __attribute__((ext_vector_type(8)));

// fp32 -> bf16 hi (truncated) + exact residual; RNE for the lo piece.
__device__ __forceinline__ short bf_hi(float v, float& rem) {
  const unsigned u  = __builtin_bit_cast(unsigned, v);
  const unsigned uh = u & 0xffff0000u;
  rem = v - __builtin_bit_cast(float, uh);
  return (short)(u >> 16);
}
__device__ __forceinline__ short bf_rne(float v) {
  const unsigned u = __builtin_bit_cast(unsigned, v);
  return (short)((u + 0x7fffu + ((u >> 16) & 1u)) >> 16);
}

// ---------------------------------------------------------------------------
// K0: pre-split W into fragment-ordered bf16 hi/lo arrays (same as rounds 3-12).
// f = ((ks*4 + et)*64 + lane)*8 + j ; e = et*16+(lane&15); k = ks*32+(lane>>4)*8+j
// ---------------------------------------------------------------------------
__global__ __launch_bounds__(256) void gate_prep(
    const float* __restrict__ wgt, short* __restrict__ WH, short* __restrict__ WL)
{
  const int f  = blockIdx.x * 256 + threadIdx.x;   // 0..131071
  const int c  = f >> 11;
  const int et = (f >> 9) & 3;
  const int l  = (f >> 3) & 63;
  const int j  = f & 7;
  const int e  = et * 16 + (l & 15);
  const int k  = c * 32 + (l >> 4) * 8 + j;
  const float w = wgt[(size_t)e * Hdim + k];
  float r; const short h = bf_hi(w, r);
  WH[f] = h; WL[f] = bf_rne(r);
}

// ---------------------------------------------------------------------------
// Pipelined barrier-free engine over n k-steps (n even, >= 4).
// Per step: 10 vmem ops (W 8 + x 2); 2 steps in flight; WAITC(10) drains
// exactly the oldest step; tail 10/0. CE/CO alternate even/odd reg sets.
// ---------------------------------------------------------------------------
__device__ __forceinline__ void engine(
    const char* xr, const short* wh, const short* wl,
    int n, f32x4 (&acc)[4], unsigned voff)
{
  const char*  xp  = xr;
  const short* whp = wh;
  const short* wlp = wl;
  f32x4 P0a, P0b, P1a, P1b;                              // x, depth 2
  bf8 WEh0, WEh1, WEh2, WEh3, WEl0, WEl1, WEl2, WEl3;    // W even set
  bf8 WOh0, WOh1, WOh2, WOh3, WOl0, WOl1, WOl2, WOl3;    // W odd set

#define XLOAD(D0, D1, OA, OB)                                              \
  asm volatile("global_load_dwordx4 %0, %2, off offset:" #OA "\n\t"        \
               "global_load_dwordx4 %1, %2, off offset:" #OB               \
               : "=&v"(D0), "=&v"(D1) : "v"(xp))

#define WLOAD4(D0,D1,D2,D3, BASE)                                          \
  asm volatile(                                                            \
    "global_load_dwordx4 %0, %4, %5 offset:0\n\t"                          \
    "global_load_dwordx4 %1, %4, %5 offset:1024\n\t"                       \
    "global_load_dwordx4 %2, %4, %5 offset:2048\n\t"                       \
    "global_load_dwordx4 %3, %4, %5 offset:3072"                           \
    : "=&v"(D0), "=&v"(D1), "=&v"(D2), "=&v"(D3)                           \
    : "v"(voff), "s"(BASE))

#define WSTG(H0,H1,H2,H3, L0,L1,L2,L3) {                                   \
    WLOAD4(H0,H1,H2,H3, whp);                                              \
    WLOAD4(L0,L1,L2,L3, wlp);                                              \
    whp += 2048; wlp += 2048; }

#define WAITC(VM)                                                          \
  asm volatile("s_waitcnt vmcnt(" #VM ")" ::: "memory");                   \
  __builtin_amdgcn_sched_barrier(0);

#define COMP(XA, XB, H0,H1,H2,H3, L0,L1,L2,L3) {                                  \
    bf8 ah, al;                                                                   \
    _Pragma("unroll")                                                             \
    for (int j = 0; j < 4; ++j) { float r_;                                       \
      ah[j]     = bf_hi(XA[j], r_);  al[j]     = bf_rne(r_);                      \
      ah[j + 4] = bf_hi(XB[j], r_);  al[j + 4] = bf_rne(r_); }                    \
    __builtin_amdgcn_s_setprio(1);                                                \
    acc[0] = __builtin_amdgcn_mfma_f32_16x16x32_bf16(ah, H0, acc[0], 0, 0, 0);    \
    acc[0] = __builtin_amdgcn_mfma_f32_16x16x32_bf16(ah, L0, acc[0], 0, 0, 0);    \
    acc[0] = __builtin_amdgcn_mfma_f32_16x16x32_bf16(al, H0, acc[0], 0, 0, 0);    \
    acc[0] = __builtin_amdgcn_mfma_f32_16x16x32_bf16(al, L0, acc[0], 0, 0, 0);    \
    acc[1] = __builtin_amdgcn_mfma_f32_16x16x32_bf16(ah, H1, acc[1], 0, 0, 0);    \
    acc[1] = __builtin_amdgcn_mfma_f32_16x16x32_bf16(ah, L1, acc[1], 0, 0, 0);    \
    acc[1] = __builtin_amdgcn_mfma_f32_16x16x32_bf16(al, H1, acc[1], 0, 0, 0);    \
    acc[1] = __builtin_amdgcn_mfma_f32_16x16x32_bf16(al, L1, acc[1], 0, 0, 0);    \
    acc[2] = __builtin_amdgcn_mfma_f32_16x16x32_bf16(ah, H2, acc[2], 0, 0, 0);    \
    acc[2] = __builtin_amdgcn_mfma_f32_16x16x32_bf16(ah, L2, acc[2], 0, 0, 0);    \
    acc[2] = __builtin_amdgcn_mfma_f32_16x16x32_bf16(al, H2, acc[2], 0, 0, 0);    \
    acc[2] = __builtin_amdgcn_mfma_f32_16x16x32_bf16(al, L2, acc[2], 0, 0, 0);    \
    acc[3] = __builtin_amdgcn_mfma_f32_16x16x32_bf16(ah, H3, acc[3], 0, 0, 0);    \
    acc[3] = __builtin_amdgcn_mfma_f32_16x16x32_bf16(ah, L3, acc[3], 0, 0, 0);    \
    acc[3] = __builtin_amdgcn_mfma_f32_16x16x32_bf16(al, H3, acc[3], 0, 0, 0);    \
    acc[3] = __builtin_amdgcn_mfma_f32_16x16x32_bf16(al, L3, acc[3], 0, 0, 0);    \
    __builtin_amdgcn_s_setprio(0);                                                \
  }

#define CE(XA,XB) COMP(XA,XB, WEh0,WEh1,WEh2,WEh3, WEl0,WEl1,WEl2,WEl3)
#define CO(XA,XB) COMP(XA,XB, WOh0,WOh1,WOh2,WOh3, WOl0,WOl1,WOl2,WOl3)
#define WE_ WSTG(WEh0,WEh1,WEh2,WEh3, WEl0,WEl1,WEl2,WEl3)
#define WO_ WSTG(WOh0,WOh1,WOh2,WOh3, WOl0,WOl1,WOl2,WOl3)

  // prologue: steps 0,1 in flight (20 ops)
  WE_;  XLOAD(P0a, P0b, 0,   16);
  WO_;  XLOAD(P1a, P1b, 128, 144);

  #pragma unroll 1
  for (int i = 0; i < n / 2 - 1; ++i) {        // pair i computes (2i,2i+1),
    WAITC(10); CE(P0a, P0b); WE_; XLOAD(P0a, P0b, 256, 272);   // issues 2i+2
    WAITC(10); CO(P1a, P1b); WO_; XLOAD(P1a, P1b, 384, 400);   // issues 2i+3
    xp += 256;
  }
  WAITC(10); CE(P0a, P0b);                     // step n-2
  WAITC(0);  CO(P1a, P1b);                     // step n-1
#undef WE_
#undef WO_
#undef CE
#undef CO
#undef COMP
#undef WAITC
#undef WSTG
#undef WLOAD4
#undef XLOAD
}

// ---------------------------------------------------------------------------
// K1: SPLIT-K x2 + per-block K-PHASE ROTATION (HBM channel spread).
// Block = 256 thr = 4 waves = 2 token-groups x 2 k-halves; wave = 16 tokens x
// 64 experts over K=1024 (32 k-steps). Grid = T/32 = 1024 blocks.
// Phase p = (blockIdx&7)*4: block runs steps p..31 then 0..p-1 (two pipelined
// segments). Phases x k-halves put 16 distinct 512B strips of the 8KB row
// stride in flight chip-wide -> full HBM channel coverage (vs single-column
// lockstep at ~1 TB/s in R3-R12).
// ---------------------------------------------------------------------------
__global__ __launch_bounds__(256, 3) void gate_main(
    const float* __restrict__ x, const short* __restrict__ WH,
    const short* __restrict__ WL, const float* __restrict__ eb,
    float* __restrict__ out, int* __restrict__ fcnt, int* __restrict__ flist,
    float* __restrict__ probelg, int T)
{
  __shared__ float redu[2][64][17];            // 8.5 KB partial hand-off
  const int t  = threadIdx.x;
  const int wv = t >> 6;
  const int tg = wv >> 1;                      // token-group 0/1
  const int kh = wv & 1;                       // k-half 0/1
  const int ln = t & 63;
  const int tb = blockIdx.x * 32 + tg * 16;

  // x per-lane address: token tb+(ln&15), k-base kh*1024 + (ln>>4)*8
  const char* xq = (const char*)(x + (size_t)(tb + (ln & 15)) * Hdim
                                 + (size_t)kh * 1024 + (ln >> 4) * 8);
  // W: UNIFORM SGPR bases; per-wave k-half offset folded into VGPR voffset.
  const unsigned voff = (unsigned)(ln * 16) + ((unsigned)kh << 17);  // bytes

  f32x4 acc[4];
  #pragma unroll
  for (int et = 0; et < 4; ++et) acc[et] = (f32x4)0.f;

  const int p = (blockIdx.x & 7) * 4;          // k-phase, multiple of 4
  engine(xq + (size_t)p * 128, WH + (size_t)p * 2048, WL + (size_t)p * 2048,
         32 - p, acc, voff);
  if (p) engine(xq, WH, WL, p, acc, voff);

  // ---- split-K reduction: kh=1 partials -> LDS; kh=0 adds ----
  if (kh) {
    #pragma unroll
    for (int et = 0; et < 4; ++et)
      #pragma unroll
      for (int r = 0; r < 4; ++r)
        redu[tg][ln][et * 4 + r] = acc[et][r];
  }
  __syncthreads();
  if (kh) return;
  #pragma unroll
  for (int et = 0; et < 4; ++et)
    #pragma unroll
    for (int r = 0; r < 4; ++r)
      acc[et][r] += redu[tg][ln][et * 4 + r];

  // ---- fully in-register epilogue (R7-R12-verified) ----
  // lane = (g, c): g = ln>>4, c = ln&15; row = g*4+r; expert e = et*16+c.
  const int c = ln & 15, g = ln >> 4;
  float bias4[4];
  #pragma unroll
  for (int et = 0; et < 4; ++et) bias4[et] = eb[et * 16 + c];

  #pragma unroll
  for (int r = 0; r < 4; ++r) {
    const int gt = tb + g * 4 + r;
    const float z0 = acc[0][r], z1 = acc[1][r], z2 = acc[2][r], z3 = acc[3][r];
    if (gt == PROBE0) { probelg[c]      = z0; probelg[16 + c] = z1;
                        probelg[32 + c] = z2; probelg[48 + c] = z3; }
    if (gt == PROBE1) { probelg[64 + c]  = z0; probelg[80 + c]  = z1;
                        probelg[96 + c]  = z2; probelg[112 + c] = z3; }
    float m = fmaxf(fmaxf(z0, z1), fmaxf(z2, z3));
    #pragma unroll
    for (int off = 1; off < 16; off <<= 1) m = fmaxf(m, __shfl_xor(m, off, 64));
    const float p0 = expf(z0 - m), p1 = expf(z1 - m);
    const float p2 = expf(z2 - m), p3 = expf(z3 - m);
    float Zs = (p0 + p1) + (p2 + p3);
    #pragma unroll
    for (int off = 1; off < 16; off <<= 1) Zs += __shfl_xor(Zs, off, 64);
    const float inv = 1.f / Zs;
    const float s0 = p0 * inv, s1 = p1 * inv, s2 = p2 * inv, s3 = p3 * inv;
    float b0 = s0 + bias4[0], b1 = s1 + bias4[1];
    float b2 = s2 + bias4[2], b3 = s3 + bias4[3];
    float prev = 0.f, gmin = 1e30f, mys = 0.f;
    int myi = 0;
    #pragma unroll
    for (int r9 = 0; r9 < 9; ++r9) {
      float v = b0; int ie = 0;                    // in-lane argmax (ties->lower et)
      if (b1 > v) { v = b1; ie = 1; }
      if (b2 > v) { v = b2; ie = 2; }
      if (b3 > v) { v = b3; ie = 3; }
      int idx = ie * 16 + c;
      #pragma unroll
      for (int off = 1; off < 16; off <<= 1) {     // 16-lane argmax, ties->lower idx
        const float ov = __shfl_xor(v, off, 64);
        const int   oi = __shfl_xor(idx, off, 64);
        if (ov > v || (ov == v && oi < idx)) { v = ov; idx = oi; }
      }
      if (r9) gmin = fminf(gmin, prev - v);
      prev = v;
      if (r9 < 8) {
        const int oe = idx >> 4, oc = idx & 15;
        const float cand = oe == 0 ? s0 : oe == 1 ? s1 : oe == 2 ? s2 : s3;
        const float sv = __shfl(cand, g * 16 + oc, 64);   // winner's orig score
        if (c == r9) { myi = idx; mys = sv; }
        if (c == oc) {                              // eliminate winner
          if (oe == 0) b0 = -1e30f;
          else if (oe == 1) b1 = -1e30f;
          else if (oe == 2) b2 = -1e30f;
          else b3 = -1e30f;
        }
      }
    }
    float wsum = (c < 8) ? mys : 0.f;
    #pragma unroll
    for (int off = 1; off < 16; off <<= 1) wsum += __shfl_xor(wsum, off, 64);
    if (c < 8) {
      out[(size_t)gt * 8 + c] = (float)myi;                    // indices as float
      out[(size_t)T * 8 + (size_t)gt * 8 + c] = mys / (wsum + 1e-20f);
    }
    if (c == 0 && gmin < MARGIN) {
      const int pos = atomicAdd(fcnt, 1);
      if (pos < CAPF) flist[pos] = gt;
    }
  }
}

// ---------------------------------------------------------------------------
// K2: structural self-check: 2 blocks x 256 thr, each recomputes one probe
// token's 64 logits in fp32 VALU.
// ---------------------------------------------------------------------------
__global__ __launch_bounds__(256) void gate_check(
    const float* __restrict__ x, const float* __restrict__ wgt,
    const float* __restrict__ probelg, const int* __restrict__ fcnt,
    int* __restrict__ allbad)
{
  __shared__ float part[64][4];
  const int p = blockIdx.x;
  const int P = p ? PROBE1 : PROBE0;
  const int t = threadIdx.x, e = t >> 2, q = t & 3;
  const float4* xr = (const float4*)(x + (size_t)P * Hdim);
  const float4* wr = (const float4*)(wgt + (size_t)e * Hdim);
  float a = 0.f, b = 0.f, c = 0.f, d = 0.f;
  for (int i = 0; i < 128; ++i) {
    const int f4 = i * 4 + q;
    const float4 xv = xr[f4], wv = wr[f4];
    a = fmaf(xv.x, wv.x, a); b = fmaf(xv.y, wv.y, b);
    c = fmaf(xv.z, wv.z, c); d = fmaf(xv.w, wv.w, d);
  }
  part[e][q] = (a + b) + (c + d);
  __syncthreads();
  if (q == 0) {
    const float z = part[e][0] + part[e][1] + part[e][2] + part[e][3];
    if (fabsf(z - probelg[p * 64 + e]) > 0.05f) *allbad = 1;
  }
  if (t == 0 && p == 0 && *fcnt > CAPF) *allbad = 1;
}

// ---------------------------------------------------------------------------
// K3: fp64 fixup. Normal: flagged near-tie tokens. allbad: ALL tokens.
// ---------------------------------------------------------------------------
__global__ __launch_bounds__(256) void gate_fix(
    const float* __restrict__ x, const float* __restrict__ wgt,
    const float* __restrict__ eb, float* __restrict__ out,
    const int* __restrict__ fcnt, const int* __restrict__ flist,
    const int* __restrict__ allbad, int T)
{
  __shared__ float4 xl[4 * HF4];           // 32 KB
  __shared__ double part[4][64][4];        // 8 KB
  __shared__ int tks[4];
  const int bad = *allbad;
  int n = bad ? T : *fcnt;
  if (n <= 0) return;
  if (!bad && n > CAPF) n = CAPF;
  const int nb = (n + 3) >> 2;
  const int t = threadIdx.x;
  for (int b = blockIdx.x; b < nb; b += gridDim.x) {
    if (t < 4) {
      const int li = b * 4 + t;
      const int ci = li < n ? li : n - 1;      // clamp: benign duplicate work
      tks[t] = bad ? ci : flist[ci];
    }
    __syncthreads();
    {
      const int m = t >> 6, l2 = t & 63;
      const float4* src = (const float4*)x + (size_t)tks[m] * HF4;
      #pragma unroll
      for (int ii = 0; ii < 8; ++ii) xl[m * HF4 + ii * 64 + l2] = src[ii * 64 + l2];
    }
    __syncthreads();
    const int e = t >> 2, q = t & 3;          // 64 experts x 4 k-quarters
    double acc[4] = {0.0, 0.0, 0.0, 0.0};
    const float4* w4 = (const float4*)wgt + (size_t)e * HF4;
    for (int c = 0; c < 128; ++c) {
      const int f4 = c * 4 + q;
      const float4 wvv = w4[f4];
      #pragma unroll
      for (int m = 0; m < 4; ++m) {
        const float4 xv = xl[m * HF4 + f4];
        acc[m] += (double)xv.x * (double)wvv.x + (double)xv.y * (double)wvv.y
                + (double)xv.z * (double)wvv.z + (double)xv.w * (double)wvv.w;
      }
    }
    #pragma unroll
    for (int m = 0; m < 4; ++m) part[m][e][q] = acc[m];
    __syncthreads();
    {
      const int m = t >> 6, ln = t & 63;      // wave m -> token m, lane = expert
      const double z = part[m][ln][0] + part[m][ln][1] + part[m][ln][2] + part[m][ln][3];
      double mx = z;
      #pragma unroll
      for (int off = 32; off; off >>= 1) mx = fmax(mx, __shfl_xor(mx, off, 64));
      const double p = exp(z - mx);
      double Zs = p;
      #pragma unroll
      for (int off = 32; off; off >>= 1) Zs += __shfl_xor(Zs, off, 64);
      const double sco = p / Zs;
      double bsw = sco + (double)eb[ln];
      double mys = 0.0;
      int myi = 0;
      #pragma unroll
      for (int r = 0; r < 8; ++r) {
        double v = bsw;
        int idx = ln;
        #pragma unroll
        for (int off = 32; off; off >>= 1) {
          const double ov = __shfl_xor(v, off, 64);
          const int   oi = __shfl_xor(idx, off, 64);
          if (ov > v || (ov == v && oi < idx)) { v = ov; idx = oi; }
        }
        const double sv = __shfl(sco, idx, 64);
        if (ln == r)  { myi = idx; mys = sv; }
        if (ln == idx) bsw = -1.0e300;
      }
      double wsum = (ln < 8) ? mys : 0.0;
      #pragma unroll
      for (int off = 32; off; off >>= 1) wsum += __shfl_xor(wsum, off, 64);
      const int gt = tks[m];
      if (ln < 8) {
        out[(size_t)gt * 8 + ln] = (float)myi;
        out[(size_t)T * 8 + (size_t)gt * 8 + ln] = (float)(mys / (wsum + 1e-20));
      }
    }
    __syncthreads();
  }
}

extern "C" void kernel_launch(void* const* d_in, const int* in_sizes, int n_in,
                              void* d_out, int out_size, void* d_ws, size_t ws_size,
                              hipStream_t stream) {
  const float* x   = (const float*)d_in[0];
  const float* wgt = (const float*)d_in[1];
  const float* eb  = (const float*)d_in[2];
  float* out = (float*)d_out;
  const int T = in_sizes[0] / Hdim;          // 32768
  char* ws = (char*)d_ws;
  int*   fcnt    = (int*)(ws + WS_FCNT);
  int*   bad     = (int*)(ws + WS_BAD);
  float* probelg = (float*)(ws + WS_PROBE);
  int*   flist   = (int*)(ws + WS_FLIST);
  short* WH      = (short*)(ws + WS_WH);
  short* WL      = (short*)(ws + WS_WL);

  if (ws_size < WS_NEED) {                   // tiny-ws fallback: full fp64 path
    (void)hipMemsetAsync(ws, 0, 8, stream);
    (void)hipMemsetAsync(ws + WS_BAD, 1, 1, stream);   // allbad != 0
    hipLaunchKernelGGL(gate_fix, dim3(256), dim3(256), 0, stream,
                       x, wgt, eb, out, fcnt, flist, bad, T);
    return;
  }
  (void)hipMemsetAsync(ws, 0, 8, stream);    // fcnt = 0, allbad = 0
  hipLaunchKernelGGL(gate_prep, dim3(512), dim3(256), 0, stream, wgt, WH, WL);
  hipLaunchKernelGGL(gate_main, dim3(T / 32), dim3(256), 0, stream,
                     x, WH, WL, eb, out, fcnt, flist, probelg, T);
  hipLaunchKernelGGL(gate_check, dim3(2), dim3(256), 0, stream,
                     x, wgt, probelg, fcnt, bad);
  hipLaunchKernelGGL(gate_fix, dim3(256), dim3(256), 0, stream,
                     x, wgt, eb, out, fcnt, flist, bad, T);
}

// Round 14
// 159.398 us; speedup vs baseline: 1.0655x; 1.0655x over previous
//
#include <hip/hip_runtime.h>
#include <math.h>

#define Hdim   2048
#define HF4    512
#define MARGIN 2e-5f
#define CAPF   16384
#define PROBE0 1237
#define PROBE1 20011

// ws layout (byte offsets)
#define WS_FCNT  0
#define WS_BAD   4
#define WS_PROBE 64            // 128 floats (2 probe tokens x 64 logits)
#define WS_FLIST 1024          // CAPF ints = 64 KB
#define WS_WH    (128*1024)    // 131072 bf16 = 256 KB
#define WS_WL    (384*1024)    // 131072 bf16 = 256 KB
#define WS_NEED  (640*1024)

typedef float f32x4 __attribute__((ext_vector_type(4)));
typedef short bf8   __attribute__((ext_vector_type(8)));

typedef const __attribute__((address_space(1))) unsigned int ga_u32;
typedef __attribute__((address_space(3))) unsigned int la_u32;
__device__ __forceinline__ void gload16(const void* g, void* l) {
  __builtin_amdgcn_global_load_lds((ga_u32*)g, (la_u32*)l, 16, 0, 0);
}

// fp32 -> bf16 hi (truncated) + exact residual; RNE for the lo piece.
__device__ __forceinline__ short bf_hi(float v, float& rem) {
  const unsigned u  = __builtin_bit_cast(unsigned, v);
  const unsigned uh = u & 0xffff0000u;
  rem = v - __builtin_bit_cast(float, uh);
  return (short)(u >> 16);
}
__device__ __forceinline__ short bf_rne(float v) {
  const unsigned u = __builtin_bit_cast(unsigned, v);
  return (short)((u + 0x7fffu + ((u >> 16) & 1u)) >> 16);
}

// ---------------------------------------------------------------------------
// K0: pre-split W into fragment-ordered bf16 hi/lo arrays (same as rounds 3-13).
// f = ((ks*4 + et)*64 + lane)*8 + j ; e = et*16+(lane&15); k = ks*32+(lane>>4)*8+j
// ---------------------------------------------------------------------------
__global__ __launch_bounds__(256) void gate_prep(
    const float* __restrict__ wgt, short* __restrict__ WH, short* __restrict__ WL)
{
  const int f  = blockIdx.x * 256 + threadIdx.x;   // 0..131071
  const int c  = f >> 11;
  const int et = (f >> 9) & 3;
  const int l  = (f >> 3) & 63;
  const int j  = f & 7;
  const int e  = et * 16 + (l & 15);
  const int k  = c * 32 + (l >> 4) * 8 + j;
  const float w = wgt[(size_t)e * Hdim + k];
  float r; const short h = bf_hi(w, r);
  WH[f] = h; WL[f] = bf_rne(r);
}

// ---------------------------------------------------------------------------
// K1: LOW-ROW-DENSITY x staging (2 rows x 512 B per instruction) into
// wave-private LDS buffers; barrier-free; counted vmcnt; W via R12's depth-2
// register engine. 256 thr = 4 independent waves; wave = 16 tokens x 64
// experts, full K (16 buffers x 4 k-steps). Grid = T/64 = 512 blocks.
// LDS 64 KB (4 waves x 2 bufs x 8 KB) -> 2 blocks/CU.
// x swizzle: LDS unit p holds source unit p^(t&7) (source-side XOR, linear
// LDS dest); fragment reads use p = u^swz -> 2-way banks (free).
// Ledger/buffer: [XS(c+1):8] waits 16,16,8,8 ; W(4c+2..5) issued post-step.
// Prologue [XS0,W0,W1]; tail 8,8,8,0. Queue-traced incl. overwrite hazard.
// ---------------------------------------------------------------------------
__global__ __launch_bounds__(256, 2) void gate_main(
    const float* __restrict__ x, const short* __restrict__ WH,
    const short* __restrict__ WL, const float* __restrict__ eb,
    float* __restrict__ out, int* __restrict__ fcnt, int* __restrict__ flist,
    float* __restrict__ probelg, int T)
{
  __shared__ __align__(16) char xbuf[65536];   // 4 waves x 2 bufs x 8 KB
  const int t  = threadIdx.x;
  const int wv = t >> 6;
  const int ln = t & 63;
  const int tb = blockIdx.x * 64 + wv * 16;

  char* wb = xbuf + wv * 16384;                // wave-private region

  // ---- staging source addressing (2 tokens x 512 B per instruction) ----
  const int h   = ln >> 5;                     // token parity within instr
  const int l31 = ln & 31;                     // LDS unit position p
  const char* xrow = (const char*)x + (size_t)(tb + h) * 8192;
  const unsigned uo0 = (unsigned)((l31 ^ ((0 + h) & 7)) * 16);  // src unit = p^(t&7)
  const unsigned uo1 = (unsigned)((l31 ^ ((2 + h) & 7)) * 16);
  const unsigned uo2 = (unsigned)((l31 ^ ((4 + h) & 7)) * 16);
  const unsigned uo3 = (unsigned)((l31 ^ ((6 + h) & 7)) * 16);

  // ---- fragment read bases: token t16, unit u = ss*8+q*2+b at p = u^swz ----
  const int t16 = ln & 15, q = ln >> 4;
  const int swz = t16 & 7;
  const char* xr0 = wb + t16 * 512 + (((q * 2 + 0) ^ swz) * 16);
  const char* xr1 = wb + t16 * 512 + (((q * 2 + 1) ^ swz) * 16);

  const short* whp = WH;
  const short* wlp = WL;
  const unsigned voff = (unsigned)(ln * 16);

  f32x4 acc[4];
  #pragma unroll
  for (int et = 0; et < 4; ++et) acc[et] = (f32x4)0.f;

  bf8 WEh0, WEh1, WEh2, WEh3, WEl0, WEl1, WEl2, WEl3;    // W even set
  bf8 WOh0, WOh1, WOh2, WOh3, WOl0, WOl1, WOl2, WOl3;    // W odd set

#define WLOAD4(D0,D1,D2,D3, BASE)                                          \
  asm volatile(                                                            \
    "global_load_dwordx4 %0, %4, %5 offset:0\n\t"                          \
    "global_load_dwordx4 %1, %4, %5 offset:1024\n\t"                       \
    "global_load_dwordx4 %2, %4, %5 offset:2048\n\t"                       \
    "global_load_dwordx4 %3, %4, %5 offset:3072"                           \
    : "=&v"(D0), "=&v"(D1), "=&v"(D2), "=&v"(D3)                           \
    : "v"(voff), "s"(BASE))

#define WSTG(H0,H1,H2,H3, L0,L1,L2,L3) {                                   \
    WLOAD4(H0,H1,H2,H3, whp);                                              \
    WLOAD4(L0,L1,L2,L3, wlp);                                              \
    whp += 2048; wlp += 2048; }

#define WE_ WSTG(WEh0,WEh1,WEh2,WEh3, WEl0,WEl1,WEl2,WEl3)
#define WO_ WSTG(WOh0,WOh1,WOh2,WOh3, WOl0,WOl1,WOl2,WOl3)

#define WAITC(VM)                                                          \
  asm volatile("s_waitcnt vmcnt(" #VM ")" ::: "memory");                   \
  __builtin_amdgcn_sched_barrier(0);

#define XS(nb) {                                                           \
    const char* s_ = xrow + (size_t)(nb) * 512;                            \
    char* d_ = wb + (((nb) & 1) << 13);                                    \
    gload16(s_ +      0 + uo0, d_ + 0);                                    \
    gload16(s_ +  16384 + uo1, d_ + 1024);                                 \
    gload16(s_ +  32768 + uo2, d_ + 2048);                                 \
    gload16(s_ +  49152 + uo3, d_ + 3072);                                 \
    gload16(s_ +  65536 + uo0, d_ + 4096);                                 \
    gload16(s_ +  81920 + uo1, d_ + 5120);                                 \
    gload16(s_ +  98304 + uo2, d_ + 6144);                                 \
    gload16(s_ + 114688 + uo3, d_ + 7168);                                 \
  }

#define COMP(XA, XB, H0,H1,H2,H3, L0,L1,L2,L3) {                                  \
    bf8 ah, al;                                                                   \
    _Pragma("unroll")                                                             \
    for (int j = 0; j < 4; ++j) { float r_;                                       \
      ah[j]     = bf_hi(XA[j], r_);  al[j]     = bf_rne(r_);                      \
      ah[j + 4] = bf_hi(XB[j], r_);  al[j + 4] = bf_rne(r_); }                    \
    __builtin_amdgcn_s_setprio(1);                                                \
    acc[0] = __builtin_amdgcn_mfma_f32_16x16x32_bf16(ah, H0, acc[0], 0, 0, 0);    \
    acc[0] = __builtin_amdgcn_mfma_f32_16x16x32_bf16(ah, L0, acc[0], 0, 0, 0);    \
    acc[0] = __builtin_amdgcn_mfma_f32_16x16x32_bf16(al, H0, acc[0], 0, 0, 0);    \
    acc[0] = __builtin_amdgcn_mfma_f32_16x16x32_bf16(al, L0, acc[0], 0, 0, 0);    \
    acc[1] = __builtin_amdgcn_mfma_f32_16x16x32_bf16(ah, H1, acc[1], 0, 0, 0);    \
    acc[1] = __builtin_amdgcn_mfma_f32_16x16x32_bf16(ah, L1, acc[1], 0, 0, 0);    \
    acc[1] = __builtin_amdgcn_mfma_f32_16x16x32_bf16(al, H1, acc[1], 0, 0, 0);    \
    acc[1] = __builtin_amdgcn_mfma_f32_16x16x32_bf16(al, L1, acc[1], 0, 0, 0);    \
    acc[2] = __builtin_amdgcn_mfma_f32_16x16x32_bf16(ah, H2, acc[2], 0, 0, 0);    \
    acc[2] = __builtin_amdgcn_mfma_f32_16x16x32_bf16(ah, L2, acc[2], 0, 0, 0);    \
    acc[2] = __builtin_amdgcn_mfma_f32_16x16x32_bf16(al, H2, acc[2], 0, 0, 0);    \
    acc[2] = __builtin_amdgcn_mfma_f32_16x16x32_bf16(al, L2, acc[2], 0, 0, 0);    \
    acc[3] = __builtin_amdgcn_mfma_f32_16x16x32_bf16(ah, H3, acc[3], 0, 0, 0);    \
    acc[3] = __builtin_amdgcn_mfma_f32_16x16x32_bf16(ah, L3, acc[3], 0, 0, 0);    \
    acc[3] = __builtin_amdgcn_mfma_f32_16x16x32_bf16(al, H3, acc[3], 0, 0, 0);    \
    acc[3] = __builtin_amdgcn_mfma_f32_16x16x32_bf16(al, L3, acc[3], 0, 0, 0);    \
    __builtin_amdgcn_s_setprio(0);                                                \
  }

#define STEPE(BO, SS, VM) {                                                \
    WAITC(VM);                                                             \
    f32x4 Af0 = *(const f32x4*)(xr0 + (BO) + (SS) * 128);                  \
    f32x4 Af1 = *(const f32x4*)(xr1 + (BO) + (SS) * 128);                  \
    COMP(Af0, Af1, WEh0,WEh1,WEh2,WEh3, WEl0,WEl1,WEl2,WEl3);              \
  }
#define STEPO(BO, SS, VM) {                                                \
    WAITC(VM);                                                             \
    f32x4 Af0 = *(const f32x4*)(xr0 + (BO) + (SS) * 128);                  \
    f32x4 Af1 = *(const f32x4*)(xr1 + (BO) + (SS) * 128);                  \
    COMP(Af0, Af1, WOh0,WOh1,WOh2,WOh3, WOl0,WOl1,WOl2,WOl3);              \
  }

  // prologue: queue = [XS(0):8, W(0):8, W(1):8]
  XS(0);
  WE_;   // W(0)
  WO_;   // W(1)

  #pragma unroll 1
  for (int c = 0; c < 15; ++c) {               // buffers 0..14 (steps 4c..4c+3)
    const int bo = (c & 1) << 13;
    asm volatile("s_waitcnt lgkmcnt(0)" ::: "memory");   // prior buf reads done
    __builtin_amdgcn_sched_barrier(0);
    XS(c + 1);
    STEPE(bo, 0, 16); WE_;                     // drains XS(c)+W(4c); issue W(4c+2)
    STEPO(bo, 1, 16); WO_;                     // drains W(4c+1);     issue W(4c+3)
    STEPE(bo, 2, 8);  WE_;                     // drains [XS(c+1)]+W(4c+2); W(4c+4)
    STEPO(bo, 3, 8);  WO_;                     // drains W(4c+3);     issue W(4c+5)
  }
  // tail buffer 15 (bo = 8192): entry queue [W(60):8, W(61):8]
  STEPE(8192, 0, 8); WE_;                      // drains W(60); issue W(62)
  STEPO(8192, 1, 8); WO_;                      // drains W(61); issue W(63)
  STEPE(8192, 2, 8);                           // drains W(62)
  STEPO(8192, 3, 0);                           // drains W(63)
#undef STEPO
#undef STEPE
#undef COMP
#undef XS
#undef WAITC
#undef WE_
#undef WO_
#undef WSTG
#undef WLOAD4

  // ---- fully in-register epilogue (R7-R13-verified) ----
  // lane = (g, c): g = ln>>4, c = ln&15; row = g*4+r; expert e = et*16+c.
  const int c = ln & 15, g = ln >> 4;
  float bias4[4];
  #pragma unroll
  for (int et = 0; et < 4; ++et) bias4[et] = eb[et * 16 + c];

  #pragma unroll
  for (int r = 0; r < 4; ++r) {
    const int gt = tb + g * 4 + r;
    const float z0 = acc[0][r], z1 = acc[1][r], z2 = acc[2][r], z3 = acc[3][r];
    if (gt == PROBE0) { probelg[c]      = z0; probelg[16 + c] = z1;
                        probelg[32 + c] = z2; probelg[48 + c] = z3; }
    if (gt == PROBE1) { probelg[64 + c]  = z0; probelg[80 + c]  = z1;
                        probelg[96 + c]  = z2; probelg[112 + c] = z3; }
    float m = fmaxf(fmaxf(z0, z1), fmaxf(z2, z3));
    #pragma unroll
    for (int off = 1; off < 16; off <<= 1) m = fmaxf(m, __shfl_xor(m, off, 64));
    const float p0 = expf(z0 - m), p1 = expf(z1 - m);
    const float p2 = expf(z2 - m), p3 = expf(z3 - m);
    float Zs = (p0 + p1) + (p2 + p3);
    #pragma unroll
    for (int off = 1; off < 16; off <<= 1) Zs += __shfl_xor(Zs, off, 64);
    const float inv = 1.f / Zs;
    const float s0 = p0 * inv, s1 = p1 * inv, s2 = p2 * inv, s3 = p3 * inv;
    float b0 = s0 + bias4[0], b1 = s1 + bias4[1];
    float b2 = s2 + bias4[2], b3 = s3 + bias4[3];
    float prev = 0.f, gmin = 1e30f, mys = 0.f;
    int myi = 0;
    #pragma unroll
    for (int r9 = 0; r9 < 9; ++r9) {
      float v = b0; int ie = 0;                    // in-lane argmax (ties->lower et)
      if (b1 > v) { v = b1; ie = 1; }
      if (b2 > v) { v = b2; ie = 2; }
      if (b3 > v) { v = b3; ie = 3; }
      int idx = ie * 16 + c;
      #pragma unroll
      for (int off = 1; off < 16; off <<= 1) {     // 16-lane argmax, ties->lower idx
        const float ov = __shfl_xor(v, off, 64);
        const int   oi = __shfl_xor(idx, off, 64);
        if (ov > v || (ov == v && oi < idx)) { v = ov; idx = oi; }
      }
      if (r9) gmin = fminf(gmin, prev - v);
      prev = v;
      if (r9 < 8) {
        const int oe = idx >> 4, oc = idx & 15;
        const float cand = oe == 0 ? s0 : oe == 1 ? s1 : oe == 2 ? s2 : s3;
        const float sv = __shfl(cand, g * 16 + oc, 64);   // winner's orig score
        if (c == r9) { myi = idx; mys = sv; }
        if (c == oc) {                              // eliminate winner
          if (oe == 0) b0 = -1e30f;
          else if (oe == 1) b1 = -1e30f;
          else if (oe == 2) b2 = -1e30f;
          else b3 = -1e30f;
        }
      }
    }
    float wsum = (c < 8) ? mys : 0.f;
    #pragma unroll
    for (int off = 1; off < 16; off <<= 1) wsum += __shfl_xor(wsum, off, 64);
    if (c < 8) {
      out[(size_t)gt * 8 + c] = (float)myi;                    // indices as float
      out[(size_t)T * 8 + (size_t)gt * 8 + c] = mys / (wsum + 1e-20f);
    }
    if (c == 0 && gmin < MARGIN) {
      const int pos = atomicAdd(fcnt, 1);
      if (pos < CAPF) flist[pos] = gt;
    }
  }
}

// ---------------------------------------------------------------------------
// K2: structural self-check: 2 blocks x 256 thr, each recomputes one probe
// token's 64 logits in fp32 VALU.
// ---------------------------------------------------------------------------
__global__ __launch_bounds__(256) void gate_check(
    const float* __restrict__ x, const float* __restrict__ wgt,
    const float* __restrict__ probelg, const int* __restrict__ fcnt,
    int* __restrict__ allbad)
{
  __shared__ float part[64][4];
  const int p = blockIdx.x;
  const int P = p ? PROBE1 : PROBE0;
  const int t = threadIdx.x, e = t >> 2, q = t & 3;
  const float4* xr = (const float4*)(x + (size_t)P * Hdim);
  const float4* wr = (const float4*)(wgt + (size_t)e * Hdim);
  float a = 0.f, b = 0.f, c = 0.f, d = 0.f;
  for (int i = 0; i < 128; ++i) {
    const int f4 = i * 4 + q;
    const float4 xv = xr[f4], wv = wr[f4];
    a = fmaf(xv.x, wv.x, a); b = fmaf(xv.y, wv.y, b);
    c = fmaf(xv.z, wv.z, c); d = fmaf(xv.w, wv.w, d);
  }
  part[e][q] = (a + b) + (c + d);
  __syncthreads();
  if (q == 0) {
    const float z = part[e][0] + part[e][1] + part[e][2] + part[e][3];
    if (fabsf(z - probelg[p * 64 + e]) > 0.05f) *allbad = 1;
  }
  if (t == 0 && p == 0 && *fcnt > CAPF) *allbad = 1;
}

// ---------------------------------------------------------------------------
// K3: fp64 fixup. Normal: flagged near-tie tokens. allbad: ALL tokens.
// ---------------------------------------------------------------------------
__global__ __launch_bounds__(256) void gate_fix(
    const float* __restrict__ x, const float* __restrict__ wgt,
    const float* __restrict__ eb, float* __restrict__ out,
    const int* __restrict__ fcnt, const int* __restrict__ flist,
    const int* __restrict__ allbad, int T)
{
  __shared__ float4 xl[4 * HF4];           // 32 KB
  __shared__ double part[4][64][4];        // 8 KB
  __shared__ int tks[4];
  const int bad = *allbad;
  int n = bad ? T : *fcnt;
  if (n <= 0) return;
  if (!bad && n > CAPF) n = CAPF;
  const int nb = (n + 3) >> 2;
  const int t = threadIdx.x;
  for (int b = blockIdx.x; b < nb; b += gridDim.x) {
    if (t < 4) {
      const int li = b * 4 + t;
      const int ci = li < n ? li : n - 1;      // clamp: benign duplicate work
      tks[t] = bad ? ci : flist[ci];
    }
    __syncthreads();
    {
      const int m = t >> 6, l2 = t & 63;
      const float4* src = (const float4*)x + (size_t)tks[m] * HF4;
      #pragma unroll
      for (int ii = 0; ii < 8; ++ii) xl[m * HF4 + ii * 64 + l2] = src[ii * 64 + l2];
    }
    __syncthreads();
    const int e = t >> 2, q = t & 3;          // 64 experts x 4 k-quarters
    double acc[4] = {0.0, 0.0, 0.0, 0.0};
    const float4* w4 = (const float4*)wgt + (size_t)e * HF4;
    for (int c = 0; c < 128; ++c) {
      const int f4 = c * 4 + q;
      const float4 wvv = w4[f4];
      #pragma unroll
      for (int m = 0; m < 4; ++m) {
        const float4 xv = xl[m * HF4 + f4];
        acc[m] += (double)xv.x * (double)wvv.x + (double)xv.y * (double)wvv.y
                + (double)xv.z * (double)wvv.z + (double)xv.w * (double)wvv.w;
      }
    }
    #pragma unroll
    for (int m = 0; m < 4; ++m) part[m][e][q] = acc[m];
    __syncthreads();
    {
      const int m = t >> 6, ln = t & 63;      // wave m -> token m, lane = expert
      const double z = part[m][ln][0] + part[m][ln][1] + part[m][ln][2] + part[m][ln][3];
      double mx = z;
      #pragma unroll
      for (int off = 32; off; off >>= 1) mx = fmax(mx, __shfl_xor(mx, off, 64));
      const double p = exp(z - mx);
      double Zs = p;
      #pragma unroll
      for (int off = 32; off; off >>= 1) Zs += __shfl_xor(Zs, off, 64);
      const double sco = p / Zs;
      double bsw = sco + (double)eb[ln];
      double mys = 0.0;
      int myi = 0;
      #pragma unroll
      for (int r = 0; r < 8; ++r) {
        double v = bsw;
        int idx = ln;
        #pragma unroll
        for (int off = 32; off; off >>= 1) {
          const double ov = __shfl_xor(v, off, 64);
          const int   oi = __shfl_xor(idx, off, 64);
          if (ov > v || (ov == v && oi < idx)) { v = ov; idx = oi; }
        }
        const double sv = __shfl(sco, idx, 64);
        if (ln == r)  { myi = idx; mys = sv; }
        if (ln == idx) bsw = -1.0e300;
      }
      double wsum = (ln < 8) ? mys : 0.0;
      #pragma unroll
      for (int off = 32; off; off >>= 1) wsum += __shfl_xor(wsum, off, 64);
      const int gt = tks[m];
      if (ln < 8) {
        out[(size_t)gt * 8 + ln] = (float)myi;
        out[(size_t)T * 8 + (size_t)gt * 8 + ln] = (float)(mys / (wsum + 1e-20));
      }
    }
    __syncthreads();
  }
}

extern "C" void kernel_launch(void* const* d_in, const int* in_sizes, int n_in,
                              void* d_out, int out_size, void* d_ws, size_t ws_size,
                              hipStream_t stream) {
  const float* x   = (const float*)d_in[0];
  const float* wgt = (const float*)d_in[1];
  const float* eb  = (const float*)d_in[2];
  float* out = (float*)d_out;
  const int T = in_sizes[0] / Hdim;          // 32768
  char* ws = (char*)d_ws;
  int*   fcnt    = (int*)(ws + WS_FCNT);
  int*   bad     = (int*)(ws + WS_BAD);
  float* probelg = (float*)(ws + WS_PROBE);
  int*   flist   = (int*)(ws + WS_FLIST);
  short* WH      = (short*)(ws + WS_WH);
  short* WL      = (short*)(ws + WS_WL);

  if (ws_size < WS_NEED) {                   // tiny-ws fallback: full fp64 path
    (void)hipMemsetAsync(ws, 0, 8, stream);
    (void)hipMemsetAsync(ws + WS_BAD, 1, 1, stream);   // allbad != 0
    hipLaunchKernelGGL(gate_fix, dim3(256), dim3(256), 0, stream,
                       x, wgt, eb, out, fcnt, flist, bad, T);
    return;
  }
  (void)hipMemsetAsync(ws, 0, 8, stream);    // fcnt = 0, allbad = 0
  hipLaunchKernelGGL(gate_prep, dim3(512), dim3(256), 0, stream, wgt, WH, WL);
  hipLaunchKernelGGL(gate_main, dim3(T / 64), dim3(256), 0, stream,
                     x, WH, WL, eb, out, fcnt, flist, probelg, T);
  hipLaunchKernelGGL(gate_check, dim3(2), dim3(256), 0, stream,
                     x, wgt, probelg, fcnt, bad);
  hipLaunchKernelGGL(gate_fix, dim3(256), dim3(256), 0, stream,
                     x, wgt, eb, out, fcnt, flist, bad, T);
}

// Round 15
// 139.300 us; speedup vs baseline: 1.2192x; 1.1443x over previous
//
#include <hip/hip_runtime.h>
#include <math.h>

#define Hdim   2048
#define HF4    512
#define MARGIN 2e-5f
#define CAPF   16384
#define PROBE0 1237
#define PROBE1 20011

// ws layout (byte offsets)
#define WS_FCNT  0
#define WS_BAD   4
#define WS_PROBE 64            // 128 floats (2 probe tokens x 64 logits)
#define WS_FLIST 1024          // CAPF ints = 64 KB
#define WS_WH    (128*1024)    // 131072 bf16 = 256 KB
#define WS_WL    (384*1024)    // 131072 bf16 = 256 KB
#define WS_NEED  (640*1024)

typedef float f32x4 __attribute__((ext_vector_type(4)));
typedef short bf8   __attribute__((ext_vector_type(8)));

typedef const __attribute__((address_space(1))) unsigned int ga_u32;
typedef __attribute__((address_space(3))) unsigned int la_u32;
__device__ __forceinline__ void gload16(const void* g, void* l) {
  __builtin_amdgcn_global_load_lds((ga_u32*)g, (la_u32*)l, 16, 0, 0);
}

// fp32 -> bf16 hi (truncated) + exact residual; RNE for the lo piece.
__device__ __forceinline__ short bf_hi(float v, float& rem) {
  const unsigned u  = __builtin_bit_cast(unsigned, v);
  const unsigned uh = u & 0xffff0000u;
  rem = v - __builtin_bit_cast(float, uh);
  return (short)(u >> 16);
}
__device__ __forceinline__ short bf_rne(float v) {
  const unsigned u = __builtin_bit_cast(unsigned, v);
  return (short)((u + 0x7fffu + ((u >> 16) & 1u)) >> 16);
}

// ---------------------------------------------------------------------------
// K0: pre-split W into fragment-ordered bf16 hi/lo arrays (same as rounds 3-14)
// + reset of fcnt/allbad (replaces the in-graph hipMemsetAsync).
// f = ((ks*4 + et)*64 + lane)*8 + j ; e = et*16+(lane&15); k = ks*32+(lane>>4)*8+j
// ---------------------------------------------------------------------------
__global__ __launch_bounds__(256) void gate_prep(
    const float* __restrict__ wgt, short* __restrict__ WH, short* __restrict__ WL,
    int* __restrict__ fcnt, int* __restrict__ allbad)
{
  if (blockIdx.x == 0 && threadIdx.x == 0) { *fcnt = 0; *allbad = 0; }
  const int f  = blockIdx.x * 256 + threadIdx.x;   // 0..131071
  const int c  = f >> 11;
  const int et = (f >> 9) & 3;
  const int l  = (f >> 3) & 63;
  const int j  = f & 7;
  const int e  = et * 16 + (l & 15);
  const int k  = c * 32 + (l >> 4) * 8 + j;
  const float w = wgt[(size_t)e * Hdim + k];
  float r; const short h = bf_hi(w, r);
  WH[f] = h; WL[f] = bf_rne(r);
}

// ---------------------------------------------------------------------------
// K1 (R7-verified, empirical best): LDS-staged (3-slot, distance-1, vmcnt(4))
// split-bf16 MFMA gate with fully in-register epilogue.
// 256 thr = 4 waves; wave = 16 tokens x 64 experts; block = 64 tokens.
// 3 slots x 16 KB: [x 8K | Whi 4K | Wlo 4K] -> 48 KB LDS -> 3 blocks/CU.
// Epilogue: C/D layout => 16-lane group g holds rows g*4+r (reg r) with
// expert = et*16 + (lane&15); softmax/top-9 via 16-wide shfl, 4 rows parallel.
// ---------------------------------------------------------------------------
__global__ __launch_bounds__(256, 3) void gate_main(
    const float* __restrict__ x, const short* __restrict__ WH,
    const short* __restrict__ WL, const float* __restrict__ eb,
    float* __restrict__ out, int* __restrict__ fcnt, int* __restrict__ flist,
    float* __restrict__ probelg, int T)
{
  __shared__ __align__(16) char smem[49152];       // 3 slots x 16 KB
  const int t    = threadIdx.x;
  const int wv   = t >> 6;
  const int ln   = t & 63;
  const int tokb = blockIdx.x * 64;
  const int tb   = tokb + wv * 16;

  // ---- stage source addresses (per lane) ----
  const int l3 = ln >> 3;                           // token-in-8 for staging
  const int sx = (ln & 7) ^ (l3 & 6);               // swizzled source slot
  const float* xsrc0 = x + (size_t)(tokb + (wv * 2 + 0) * 8 + l3) * Hdim + sx * 4;
  const float* xsrc1 = x + (size_t)(tokb + (wv * 2 + 1) * 8 + l3) * Hdim + sx * 4;
  const short* whsrc = WH + wv * 512 + ln * 8;      // + ks*2048
  const short* wlsrc = WL + wv * 512 + ln * 8;

  // ---- fragment read offsets ----
  // A: token tk = wv*16+(ln&15); logical slot a=(ln>>4)*2; physical a^(ln&6)
  const int Aoff = (wv * 16 + (ln & 15)) * 32 + ((((ln >> 4) * 2) ^ (ln & 6)) * 4);

  f32x4 acc[4];
  #pragma unroll
  for (int et = 0; et < 4; ++et) acc[et] = (f32x4)0.f;

#define STAGE(kk, SL) {                                                    \
    char* sl_ = smem + ((SL) * 16384);                                     \
    gload16(xsrc0 + (kk) * 32, sl_ + (wv * 2 + 0) * 1024);                 \
    gload16(xsrc1 + (kk) * 32, sl_ + (wv * 2 + 1) * 1024);                 \
    gload16(whsrc + (size_t)(kk) * 2048, sl_ + 8192  + wv * 1024);         \
    gload16(wlsrc + (size_t)(kk) * 2048, sl_ + 12288 + wv * 1024);         \
  }

#define STEP(kk, SC, SN, WAITN) {                                          \
    if ((kk) < 63) STAGE((kk) + 1, SN);                                    \
    asm volatile("s_waitcnt vmcnt(" #WAITN ")" ::: "memory");              \
    __builtin_amdgcn_s_barrier();                                          \
    const char*  sl_ = smem + ((SC) * 16384);                              \
    const float* xs_ = (const float*)sl_;                                  \
    f32x4 Af0 = *(const f32x4*)(xs_ + Aoff);                               \
    f32x4 Af1 = *(const f32x4*)(xs_ + Aoff + 4);                           \
    const short* bh_ = (const short*)(sl_ + 8192)  + ln * 8;               \
    const short* bl_ = (const short*)(sl_ + 12288) + ln * 8;               \
    bf8 Bh0 = *(const bf8*)(bh_);                                          \
    bf8 Bh1 = *(const bf8*)(bh_ + 512);                                    \
    bf8 Bh2 = *(const bf8*)(bh_ + 1024);                                   \
    bf8 Bh3 = *(const bf8*)(bh_ + 1536);                                   \
    bf8 Bl0 = *(const bf8*)(bl_);                                          \
    bf8 Bl1 = *(const bf8*)(bl_ + 512);                                    \
    bf8 Bl2 = *(const bf8*)(bl_ + 1024);                                   \
    bf8 Bl3 = *(const bf8*)(bl_ + 1536);                                   \
    asm volatile("s_waitcnt lgkmcnt(0)" ::: "memory");                     \
    __builtin_amdgcn_sched_barrier(0);                                     \
    bf8 ah, al;                                                            \
    _Pragma("unroll")                                                      \
    for (int j = 0; j < 4; ++j) {                                          \
      float r_;                                                            \
      ah[j]     = bf_hi(Af0[j], r_);  al[j]     = bf_rne(r_);              \
      ah[j + 4] = bf_hi(Af1[j], r_);  al[j + 4] = bf_rne(r_);              \
    }                                                                      \
    acc[0] = __builtin_amdgcn_mfma_f32_16x16x32_bf16(ah, Bh0, acc[0], 0, 0, 0); \
    acc[0] = __builtin_amdgcn_mfma_f32_16x16x32_bf16(ah, Bl0, acc[0], 0, 0, 0); \
    acc[0] = __builtin_amdgcn_mfma_f32_16x16x32_bf16(al, Bh0, acc[0], 0, 0, 0); \
    acc[0] = __builtin_amdgcn_mfma_f32_16x16x32_bf16(al, Bl0, acc[0], 0, 0, 0); \
    acc[1] = __builtin_amdgcn_mfma_f32_16x16x32_bf16(ah, Bh1, acc[1], 0, 0, 0); \
    acc[1] = __builtin_amdgcn_mfma_f32_16x16x32_bf16(ah, Bl1, acc[1], 0, 0, 0); \
    acc[1] = __builtin_amdgcn_mfma_f32_16x16x32_bf16(al, Bh1, acc[1], 0, 0, 0); \
    acc[1] = __builtin_amdgcn_mfma_f32_16x16x32_bf16(al, Bl1, acc[1], 0, 0, 0); \
    acc[2] = __builtin_amdgcn_mfma_f32_16x16x32_bf16(ah, Bh2, acc[2], 0, 0, 0); \
    acc[2] = __builtin_amdgcn_mfma_f32_16x16x32_bf16(ah, Bl2, acc[2], 0, 0, 0); \
    acc[2] = __builtin_amdgcn_mfma_f32_16x16x32_bf16(al, Bh2, acc[2], 0, 0, 0); \
    acc[2] = __builtin_amdgcn_mfma_f32_16x16x32_bf16(al, Bl2, acc[2], 0, 0, 0); \
    acc[3] = __builtin_amdgcn_mfma_f32_16x16x32_bf16(ah, Bh3, acc[3], 0, 0, 0); \
    acc[3] = __builtin_amdgcn_mfma_f32_16x16x32_bf16(ah, Bl3, acc[3], 0, 0, 0); \
    acc[3] = __builtin_amdgcn_mfma_f32_16x16x32_bf16(al, Bh3, acc[3], 0, 0, 0); \
    acc[3] = __builtin_amdgcn_mfma_f32_16x16x32_bf16(al, Bl3, acc[3], 0, 0, 0); \
  }

  STAGE(0, 0);
  #pragma unroll 1
  for (int ks = 0; ks < 63; ks += 3) {             // trios 0..62
    STEP(ks,     0, 1, 4);
    STEP(ks + 1, 1, 2, 4);
    STEP(ks + 2, 2, 0, 4);
  }
  STEP(63, 0, 0, 0);                               // final: no stage, drain
#undef STEP
#undef STAGE

  // ---- fully in-register epilogue ----
  // lane = (g, c): g = ln>>4 group, c = ln&15. Row (within wave) = g*4+r,
  // expert e = et*16+c with value acc[et][r]. 16-wide shfl keeps groups.
  const int c = ln & 15, g = ln >> 4;
  float bias4[4];
  #pragma unroll
  for (int et = 0; et < 4; ++et) bias4[et] = eb[et * 16 + c];

  #pragma unroll
  for (int r = 0; r < 4; ++r) {
    const int gt = tb + g * 4 + r;
    const float z0 = acc[0][r], z1 = acc[1][r], z2 = acc[2][r], z3 = acc[3][r];
    if (gt == PROBE0) { probelg[c]      = z0; probelg[16 + c] = z1;
                        probelg[32 + c] = z2; probelg[48 + c] = z3; }
    if (gt == PROBE1) { probelg[64 + c]  = z0; probelg[80 + c]  = z1;
                        probelg[96 + c]  = z2; probelg[112 + c] = z3; }
    float m = fmaxf(fmaxf(z0, z1), fmaxf(z2, z3));
    #pragma unroll
    for (int off = 1; off < 16; off <<= 1) m = fmaxf(m, __shfl_xor(m, off, 64));
    const float p0 = expf(z0 - m), p1 = expf(z1 - m);
    const float p2 = expf(z2 - m), p3 = expf(z3 - m);
    float Zs = (p0 + p1) + (p2 + p3);
    #pragma unroll
    for (int off = 1; off < 16; off <<= 1) Zs += __shfl_xor(Zs, off, 64);
    const float inv = 1.f / Zs;
    const float s0 = p0 * inv, s1 = p1 * inv, s2 = p2 * inv, s3 = p3 * inv;
    float b0 = s0 + bias4[0], b1 = s1 + bias4[1];
    float b2 = s2 + bias4[2], b3 = s3 + bias4[3];
    float prev = 0.f, gmin = 1e30f, mys = 0.f;
    int myi = 0;
    #pragma unroll
    for (int r9 = 0; r9 < 9; ++r9) {
      float v = b0; int ie = 0;                    // in-lane argmax (ties->lower et)
      if (b1 > v) { v = b1; ie = 1; }
      if (b2 > v) { v = b2; ie = 2; }
      if (b3 > v) { v = b3; ie = 3; }
      int idx = ie * 16 + c;
      #pragma unroll
      for (int off = 1; off < 16; off <<= 1) {     // 16-lane argmax, ties->lower idx
        const float ov = __shfl_xor(v, off, 64);
        const int   oi = __shfl_xor(idx, off, 64);
        if (ov > v || (ov == v && oi < idx)) { v = ov; idx = oi; }
      }
      if (r9) gmin = fminf(gmin, prev - v);
      prev = v;
      if (r9 < 8) {
        const int oe = idx >> 4, oc = idx & 15;
        const float cand = oe == 0 ? s0 : oe == 1 ? s1 : oe == 2 ? s2 : s3;
        const float sv = __shfl(cand, g * 16 + oc, 64);   // winner's orig score
        if (c == r9) { myi = idx; mys = sv; }
        if (c == oc) {                              // eliminate winner
          if (oe == 0) b0 = -1e30f;
          else if (oe == 1) b1 = -1e30f;
          else if (oe == 2) b2 = -1e30f;
          else b3 = -1e30f;
        }
      }
    }
    float wsum = (c < 8) ? mys : 0.f;
    #pragma unroll
    for (int off = 1; off < 16; off <<= 1) wsum += __shfl_xor(wsum, off, 64);
    if (c < 8) {
      out[(size_t)gt * 8 + c] = (float)myi;                    // indices as float
      out[(size_t)T * 8 + (size_t)gt * 8 + c] = mys / (wsum + 1e-20f);
    }
    if (c == 0 && gmin < MARGIN) {
      const int pos = atomicAdd(fcnt, 1);
      if (pos < CAPF) flist[pos] = gt;
    }
  }
}

// ---------------------------------------------------------------------------
// K2: structural self-check: 2 blocks x 256 thr, each recomputes one probe
// token's 64 logits in fp32 VALU.
// ---------------------------------------------------------------------------
__global__ __launch_bounds__(256) void gate_check(
    const float* __restrict__ x, const float* __restrict__ wgt,
    const float* __restrict__ probelg, const int* __restrict__ fcnt,
    int* __restrict__ allbad)
{
  __shared__ float part[64][4];
  const int p = blockIdx.x;
  const int P = p ? PROBE1 : PROBE0;
  const int t = threadIdx.x, e = t >> 2, q = t & 3;
  const float4* xr = (const float4*)(x + (size_t)P * Hdim);
  const float4* wr = (const float4*)(wgt + (size_t)e * Hdim);
  float a = 0.f, b = 0.f, c = 0.f, d = 0.f;
  for (int i = 0; i < 128; ++i) {
    const int f4 = i * 4 + q;
    const float4 xv = xr[f4], wv = wr[f4];
    a = fmaf(xv.x, wv.x, a); b = fmaf(xv.y, wv.y, b);
    c = fmaf(xv.z, wv.z, c); d = fmaf(xv.w, wv.w, d);
  }
  part[e][q] = (a + b) + (c + d);
  __syncthreads();
  if (q == 0) {
    const float z = part[e][0] + part[e][1] + part[e][2] + part[e][3];
    if (fabsf(z - probelg[p * 64 + e]) > 0.05f) *allbad = 1;
  }
  if (t == 0 && p == 0 && *fcnt > CAPF) *allbad = 1;
}

// ---------------------------------------------------------------------------
// K3: fp64 fixup. Normal: flagged near-tie tokens. allbad: ALL tokens.
// ---------------------------------------------------------------------------
__global__ __launch_bounds__(256) void gate_fix(
    const float* __restrict__ x, const float* __restrict__ wgt,
    const float* __restrict__ eb, float* __restrict__ out,
    const int* __restrict__ fcnt, const int* __restrict__ flist,
    const int* __restrict__ allbad, int T)
{
  __shared__ float4 xl[4 * HF4];           // 32 KB
  __shared__ double part[4][64][4];        // 8 KB
  __shared__ int tks[4];
  const int bad = *allbad;
  int n = bad ? T : *fcnt;
  if (n <= 0) return;
  if (!bad && n > CAPF) n = CAPF;
  const int nb = (n + 3) >> 2;
  const int t = threadIdx.x;
  for (int b = blockIdx.x; b < nb; b += gridDim.x) {
    if (t < 4) {
      const int li = b * 4 + t;
      const int ci = li < n ? li : n - 1;      // clamp: benign duplicate work
      tks[t] = bad ? ci : flist[ci];
    }
    __syncthreads();
    {
      const int m = t >> 6, l2 = t & 63;
      const float4* src = (const float4*)x + (size_t)tks[m] * HF4;
      #pragma unroll
      for (int ii = 0; ii < 8; ++ii) xl[m * HF4 + ii * 64 + l2] = src[ii * 64 + l2];
    }
    __syncthreads();
    const int e = t >> 2, q = t & 3;          // 64 experts x 4 k-quarters
    double acc[4] = {0.0, 0.0, 0.0, 0.0};
    const float4* w4 = (const float4*)wgt + (size_t)e * HF4;
    for (int c = 0; c < 128; ++c) {
      const int f4 = c * 4 + q;
      const float4 wvv = w4[f4];
      #pragma unroll
      for (int m = 0; m < 4; ++m) {
        const float4 xv = xl[m * HF4 + f4];
        acc[m] += (double)xv.x * (double)wvv.x + (double)xv.y * (double)wvv.y
                + (double)xv.z * (double)wvv.z + (double)xv.w * (double)wvv.w;
      }
    }
    #pragma unroll
    for (int m = 0; m < 4; ++m) part[m][e][q] = acc[m];
    __syncthreads();
    {
      const int m = t >> 6, ln = t & 63;      // wave m -> token m, lane = expert
      const double z = part[m][ln][0] + part[m][ln][1] + part[m][ln][2] + part[m][ln][3];
      double mx = z;
      #pragma unroll
      for (int off = 32; off; off >>= 1) mx = fmax(mx, __shfl_xor(mx, off, 64));
      const double p = exp(z - mx);
      double Zs = p;
      #pragma unroll
      for (int off = 32; off; off >>= 1) Zs += __shfl_xor(Zs, off, 64);
      const double sco = p / Zs;
      double bsw = sco + (double)eb[ln];
      double mys = 0.0;
      int myi = 0;
      #pragma unroll
      for (int r = 0; r < 8; ++r) {
        double v = bsw;
        int idx = ln;
        #pragma unroll
        for (int off = 32; off; off >>= 1) {
          const double ov = __shfl_xor(v, off, 64);
          const int   oi = __shfl_xor(idx, off, 64);
          if (ov > v || (ov == v && oi < idx)) { v = ov; idx = oi; }
        }
        const double sv = __shfl(sco, idx, 64);
        if (ln == r)  { myi = idx; mys = sv; }
        if (ln == idx) bsw = -1.0e300;
      }
      double wsum = (ln < 8) ? mys : 0.0;
      #pragma unroll
      for (int off = 32; off; off >>= 1) wsum += __shfl_xor(wsum, off, 64);
      const int gt = tks[m];
      if (ln < 8) {
        out[(size_t)gt * 8 + ln] = (float)myi;
        out[(size_t)T * 8 + (size_t)gt * 8 + ln] = (float)(mys / (wsum + 1e-20));
      }
    }
    __syncthreads();
  }
}

extern "C" void kernel_launch(void* const* d_in, const int* in_sizes, int n_in,
                              void* d_out, int out_size, void* d_ws, size_t ws_size,
                              hipStream_t stream) {
  const float* x   = (const float*)d_in[0];
  const float* wgt = (const float*)d_in[1];
  const float* eb  = (const float*)d_in[2];
  float* out = (float*)d_out;
  const int T = in_sizes[0] / Hdim;          // 32768
  char* ws = (char*)d_ws;
  int*   fcnt    = (int*)(ws + WS_FCNT);
  int*   bad     = (int*)(ws + WS_BAD);
  float* probelg = (float*)(ws + WS_PROBE);
  int*   flist   = (int*)(ws + WS_FLIST);
  short* WH      = (short*)(ws + WS_WH);
  short* WL      = (short*)(ws + WS_WL);

  if (ws_size < WS_NEED) {                   // tiny-ws fallback: full fp64 path
    (void)hipMemsetAsync(ws, 0, 8, stream);
    (void)hipMemsetAsync(ws + WS_BAD, 1, 1, stream);   // allbad != 0
    hipLaunchKernelGGL(gate_fix, dim3(256), dim3(256), 0, stream,
                       x, wgt, eb, out, fcnt, flist, bad, T);
    return;
  }
  // no hipMemsetAsync in the main path: gate_prep resets fcnt/allbad
  hipLaunchKernelGGL(gate_prep, dim3(512), dim3(256), 0, stream,
                     wgt, WH, WL, fcnt, bad);
  hipLaunchKernelGGL(gate_main, dim3(T / 64), dim3(256), 0, stream,
                     x, WH, WL, eb, out, fcnt, flist, probelg, T);
  hipLaunchKernelGGL(gate_check, dim3(2), dim3(256), 0, stream,
                     x, wgt, probelg, fcnt, bad);
  hipLaunchKernelGGL(gate_fix, dim3(256), dim3(256), 0, stream,
                     x, wgt, eb, out, fcnt, flist, bad, T);
}